// Round 1
// baseline (152.944 us; speedup 1.0000x reference)
//
#include <hip/hip_runtime.h>
#include <math.h>

// Problem geometry (compile-time constants)
#define DD 128
#define HH 128
#define WW 128
constexpr int   DHW   = DD * HH * WW;        // 2^21
constexpr int   BATCH = 2;
constexpr long long NTOT = (long long)BATCH * 3 * DHW;  // 12,582,912

// ---------------------------------------------------------------------------
// Kernel 1: per-voxel trilinear warp + squared-compose, block partial sums.
// One thread per (b, z, y, x). Deterministic per-block reduction.
// ---------------------------------------------------------------------------
__global__ __launch_bounds__(256)
void icl_partial_kernel(const float* __restrict__ fwd,
                        const float* __restrict__ bwd,
                        float* __restrict__ partial) {
    const int tid = blockIdx.x * blockDim.x + threadIdx.x;   // [0, B*DHW)
    const int b = tid >> 21;           // DHW = 2^21
    const int v = tid & (DHW - 1);
    const int z = v >> 14;             // H*W = 2^14
    const int y = (v >> 7) & 127;
    const int x = v & 127;

    const float* f = fwd + (size_t)b * 3 * DHW;
    const float fz = f[v];
    const float fy = f[v + DHW];
    const float fx = f[v + 2 * DHW];

    const float cz = (float)z + fz;
    const float cy = (float)y + fy;
    const float cx = (float)x + fx;

    const float z0f = floorf(cz), y0f = floorf(cy), x0f = floorf(cx);
    const float wz = cz - z0f, wy = cy - y0f, wx = cx - x0f;
    const int z0 = (int)z0f, y0 = (int)y0f, x0 = (int)x0f;

    const float* g = bwd + (size_t)b * 3 * DHW;

    float o0 = 0.f, o1 = 0.f, o2 = 0.f;
#pragma unroll
    for (int dz = 0; dz < 2; ++dz) {
        const int  zi  = z0 + dz;
        const bool vz  = (zi >= 0) & (zi < DD);
        const int  zc  = min(max(zi, 0), DD - 1);
        const float az = dz ? wz : 1.f - wz;
#pragma unroll
        for (int dy = 0; dy < 2; ++dy) {
            const int  yi  = y0 + dy;
            const bool vy  = (yi >= 0) & (yi < HH);
            const int  yc  = min(max(yi, 0), HH - 1);
            const float ay = dy ? wy : 1.f - wy;
#pragma unroll
            for (int dx = 0; dx < 2; ++dx) {
                const int  xi  = x0 + dx;
                const bool vx  = (xi >= 0) & (xi < WW);
                const int  xc  = min(max(xi, 0), WW - 1);
                const float ax = dx ? wx : 1.f - wx;

                const float w = (vz & vy & vx) ? (az * ay * ax) : 0.f;
                const int idx = (zc * HH + yc) * WW + xc;
                o0 += w * g[idx];
                o1 += w * g[idx + DHW];
                o2 += w * g[idx + 2 * DHW];
            }
        }
    }

    const float c0 = fz + o0;
    const float c1 = fy + o1;
    const float c2 = fx + o2;
    float acc = c0 * c0 + c1 * c1 + c2 * c2;

    // wave-64 shuffle reduction
#pragma unroll
    for (int off = 32; off > 0; off >>= 1)
        acc += __shfl_down(acc, off, 64);

    __shared__ float smem[4];            // 256 threads = 4 waves
    const int lane = threadIdx.x & 63;
    const int wid  = threadIdx.x >> 6;
    if (lane == 0) smem[wid] = acc;
    __syncthreads();
    if (threadIdx.x == 0) {
        partial[blockIdx.x] = smem[0] + smem[1] + smem[2] + smem[3];
    }
}

// ---------------------------------------------------------------------------
// Kernel 2: deterministic final reduction of the block partials (double),
// divide by N, nan_to_num, write scalar loss.
// ---------------------------------------------------------------------------
__global__ __launch_bounds__(256)
void icl_final_kernel(const float* __restrict__ partial, int n,
                      float* __restrict__ out) {
    double acc = 0.0;
    for (int i = threadIdx.x; i < n; i += 256)
        acc += (double)partial[i];

#pragma unroll
    for (int off = 32; off > 0; off >>= 1)
        acc += __shfl_down(acc, off, 64);

    __shared__ double smem[4];
    const int lane = threadIdx.x & 63;
    const int wid  = threadIdx.x >> 6;
    if (lane == 0) smem[wid] = acc;
    __syncthreads();
    if (threadIdx.x == 0) {
        const double total = smem[0] + smem[1] + smem[2] + smem[3];
        float r = (float)(total / (double)NTOT);
        if (isnan(r)) r = 0.f;
        else if (isinf(r)) r = (r > 0.f) ? 1000.f : 0.f;
        out[0] = r;
    }
}

// ---------------------------------------------------------------------------
extern "C" void kernel_launch(void* const* d_in, const int* in_sizes, int n_in,
                              void* d_out, int out_size, void* d_ws, size_t ws_size,
                              hipStream_t stream) {
    const float* fwd = (const float*)d_in[0];
    const float* bwd = (const float*)d_in[1];
    float* out = (float*)d_out;
    float* partial = (float*)d_ws;       // 16384 floats = 64 KB

    const int total_threads = BATCH * DHW;      // 4,194,304
    const int block = 256;
    const int grid = total_threads / block;     // 16384

    icl_partial_kernel<<<grid, block, 0, stream>>>(fwd, bwd, partial);
    icl_final_kernel<<<1, block, 0, stream>>>(partial, grid, out);
}

// Round 2
// 123.522 us; speedup vs baseline: 1.2382x; 1.2382x over previous
//
#include <hip/hip_runtime.h>
#include <math.h>

// Problem geometry (compile-time constants)
#define DD 128
#define HH 128
#define WW 128
constexpr int   DHW   = DD * HH * WW;        // 2^21
constexpr int   BATCH = 2;
constexpr long long NTOT = (long long)BATCH * 3 * DHW;  // 12,582,912

// ws layout: [0, 64KB) block partials, [64KB, 64KB + B*DHW*16) interleaved bwd
constexpr size_t WS_PARTIAL_BYTES = 65536;
constexpr size_t WS_NEEDED = WS_PARTIAL_BYTES + (size_t)BATCH * DHW * 16;

// ---------------------------------------------------------------------------
// Pre-pass: repack bwd [B,3,DHW] planes -> [B,DHW] float4 (z,y,x,0).
// 4 voxels per thread, fully coalesced.
// ---------------------------------------------------------------------------
__global__ __launch_bounds__(256)
void icl_interleave_kernel(const float* __restrict__ bwd,
                           float4* __restrict__ ibwd) {
    const int t = blockIdx.x * 256 + threadIdx.x;     // [0, B*DHW/4)
    const int b = t >> 19;                            // DHW/4 = 2^19
    const int v = (t & ((1 << 19) - 1)) << 2;
    const float* g = bwd + (size_t)b * 3 * DHW;
    const float4 a0 = *(const float4*)(g + v);
    const float4 a1 = *(const float4*)(g + v + DHW);
    const float4 a2 = *(const float4*)(g + v + 2 * DHW);
    float4* o = ibwd + (size_t)b * DHW + v;
    o[0] = make_float4(a0.x, a1.x, a2.x, 0.f);
    o[1] = make_float4(a0.y, a1.y, a2.y, 0.f);
    o[2] = make_float4(a0.z, a1.z, a2.z, 0.f);
    o[3] = make_float4(a0.w, a1.w, a2.w, 0.f);
}

// ---------------------------------------------------------------------------
// Main: 2 x-adjacent voxels per thread; 8 float4 corner gathers per voxel.
// ---------------------------------------------------------------------------
__global__ __launch_bounds__(256)
void icl_main_kernel(const float* __restrict__ fwd,
                     const float4* __restrict__ ibwd,
                     float* __restrict__ partial) {
    const int t = blockIdx.x * 256 + threadIdx.x;     // [0, B*DHW/2)
    const int b = t >> 20;                            // DHW/2 = 2^20
    const int v = (t & ((1 << 20) - 1)) << 1;         // even voxel index
    const int z = v >> 14;
    const int y = (v >> 7) & 127;
    const int x = v & 127;                            // even

    const float* f = fwd + (size_t)b * 3 * DHW;
    const float2 f0 = *(const float2*)(f + v);            // z-disp pair
    const float2 f1 = *(const float2*)(f + v + DHW);      // y-disp pair
    const float2 f2 = *(const float2*)(f + v + 2 * DHW);  // x-disp pair
    const float4* g = ibwd + (size_t)b * DHW;

    float acc = 0.f;
#pragma unroll
    for (int j = 0; j < 2; ++j) {
        const float fz = j ? f0.y : f0.x;
        const float fy = j ? f1.y : f1.x;
        const float fx = j ? f2.y : f2.x;
        const float cz = (float)z + fz;
        const float cy = (float)y + fy;
        const float cx = (float)(x + j) + fx;

        const float z0f = floorf(cz), y0f = floorf(cy), x0f = floorf(cx);
        const float wz = cz - z0f, wy = cy - y0f, wx = cx - x0f;
        const int z0 = (int)z0f, y0 = (int)y0f, x0 = (int)x0f;

        float wgt[8];
        int   idx[8];
#pragma unroll
        for (int c = 0; c < 8; ++c) {
            const int dz = c >> 2, dy = (c >> 1) & 1, dx = c & 1;
            const int zi = z0 + dz, yi = y0 + dy, xi = x0 + dx;
            const bool ok = (zi >= 0) & (zi < DD) & (yi >= 0) & (yi < HH) &
                            (xi >= 0) & (xi < WW);
            const int zc = min(max(zi, 0), DD - 1);
            const int yc = min(max(yi, 0), HH - 1);
            const int xc = min(max(xi, 0), WW - 1);
            const float az = dz ? wz : 1.f - wz;
            const float ay = dy ? wy : 1.f - wy;
            const float ax = dx ? wx : 1.f - wx;
            wgt[c] = ok ? (az * ay * ax) : 0.f;
            idx[c] = (zc * HH + yc) * WW + xc;
        }
        // issue all 8 gathers before any use
        float4 gv[8];
#pragma unroll
        for (int c = 0; c < 8; ++c) gv[c] = g[idx[c]];

        float o0 = 0.f, o1 = 0.f, o2 = 0.f;
#pragma unroll
        for (int c = 0; c < 8; ++c) {
            o0 += wgt[c] * gv[c].x;
            o1 += wgt[c] * gv[c].y;
            o2 += wgt[c] * gv[c].z;
        }
        const float c0 = fz + o0;
        const float c1 = fy + o1;
        const float c2 = fx + o2;
        acc += c0 * c0 + c1 * c1 + c2 * c2;
    }

    // wave-64 shuffle reduction
#pragma unroll
    for (int off = 32; off > 0; off >>= 1)
        acc += __shfl_down(acc, off, 64);

    __shared__ float smem[4];
    const int lane = threadIdx.x & 63;
    const int wid  = threadIdx.x >> 6;
    if (lane == 0) smem[wid] = acc;
    __syncthreads();
    if (threadIdx.x == 0)
        partial[blockIdx.x] = smem[0] + smem[1] + smem[2] + smem[3];
}

// ---------------------------------------------------------------------------
// Fallback (round-1 style): one thread per voxel, scalar gathers from planes.
// Used only if ws_size can't hold the interleave buffer.
// ---------------------------------------------------------------------------
__global__ __launch_bounds__(256)
void icl_partial_kernel(const float* __restrict__ fwd,
                        const float* __restrict__ bwd,
                        float* __restrict__ partial) {
    const int tid = blockIdx.x * blockDim.x + threadIdx.x;
    const int b = tid >> 21;
    const int v = tid & (DHW - 1);
    const int z = v >> 14;
    const int y = (v >> 7) & 127;
    const int x = v & 127;

    const float* f = fwd + (size_t)b * 3 * DHW;
    const float fz = f[v];
    const float fy = f[v + DHW];
    const float fx = f[v + 2 * DHW];

    const float cz = (float)z + fz, cy = (float)y + fy, cx = (float)x + fx;
    const float z0f = floorf(cz), y0f = floorf(cy), x0f = floorf(cx);
    const float wz = cz - z0f, wy = cy - y0f, wx = cx - x0f;
    const int z0 = (int)z0f, y0 = (int)y0f, x0 = (int)x0f;

    const float* g = bwd + (size_t)b * 3 * DHW;
    float o0 = 0.f, o1 = 0.f, o2 = 0.f;
#pragma unroll
    for (int dz = 0; dz < 2; ++dz) {
        const int zi = z0 + dz;
        const bool vz = (zi >= 0) & (zi < DD);
        const int zc = min(max(zi, 0), DD - 1);
        const float az = dz ? wz : 1.f - wz;
#pragma unroll
        for (int dy = 0; dy < 2; ++dy) {
            const int yi = y0 + dy;
            const bool vy = (yi >= 0) & (yi < HH);
            const int yc = min(max(yi, 0), HH - 1);
            const float ay = dy ? wy : 1.f - wy;
#pragma unroll
            for (int dx = 0; dx < 2; ++dx) {
                const int xi = x0 + dx;
                const bool vx = (xi >= 0) & (xi < WW);
                const int xc = min(max(xi, 0), WW - 1);
                const float ax = dx ? wx : 1.f - wx;
                const float w = (vz & vy & vx) ? (az * ay * ax) : 0.f;
                const int idx = (zc * HH + yc) * WW + xc;
                o0 += w * g[idx];
                o1 += w * g[idx + DHW];
                o2 += w * g[idx + 2 * DHW];
            }
        }
    }
    const float c0 = fz + o0, c1 = fy + o1, c2 = fx + o2;
    float acc = c0 * c0 + c1 * c1 + c2 * c2;
#pragma unroll
    for (int off = 32; off > 0; off >>= 1)
        acc += __shfl_down(acc, off, 64);
    __shared__ float smem[4];
    const int lane = threadIdx.x & 63;
    const int wid  = threadIdx.x >> 6;
    if (lane == 0) smem[wid] = acc;
    __syncthreads();
    if (threadIdx.x == 0)
        partial[blockIdx.x] = smem[0] + smem[1] + smem[2] + smem[3];
}

// ---------------------------------------------------------------------------
// Final deterministic reduction (double), divide by N, nan_to_num.
// ---------------------------------------------------------------------------
__global__ __launch_bounds__(256)
void icl_final_kernel(const float* __restrict__ partial, int n,
                      float* __restrict__ out) {
    double acc = 0.0;
    for (int i = threadIdx.x; i < n; i += 256)
        acc += (double)partial[i];
#pragma unroll
    for (int off = 32; off > 0; off >>= 1)
        acc += __shfl_down(acc, off, 64);
    __shared__ double smem[4];
    const int lane = threadIdx.x & 63;
    const int wid  = threadIdx.x >> 6;
    if (lane == 0) smem[wid] = acc;
    __syncthreads();
    if (threadIdx.x == 0) {
        const double total = smem[0] + smem[1] + smem[2] + smem[3];
        float r = (float)(total / (double)NTOT);
        if (isnan(r)) r = 0.f;
        else if (isinf(r)) r = (r > 0.f) ? 1000.f : 0.f;
        out[0] = r;
    }
}

// ---------------------------------------------------------------------------
extern "C" void kernel_launch(void* const* d_in, const int* in_sizes, int n_in,
                              void* d_out, int out_size, void* d_ws, size_t ws_size,
                              hipStream_t stream) {
    const float* fwd = (const float*)d_in[0];
    const float* bwd = (const float*)d_in[1];
    float* out = (float*)d_out;
    float* partial = (float*)d_ws;

    if (ws_size >= WS_NEEDED) {
        float4* ibwd = (float4*)((char*)d_ws + WS_PARTIAL_BYTES);
        const int grid_il   = (BATCH * DHW / 4) / 256;   // 4096
        const int grid_main = (BATCH * DHW / 2) / 256;   // 8192
        icl_interleave_kernel<<<grid_il, 256, 0, stream>>>(bwd, ibwd);
        icl_main_kernel<<<grid_main, 256, 0, stream>>>(fwd, ibwd, partial);
        icl_final_kernel<<<1, 256, 0, stream>>>(partial, grid_main, out);
    } else {
        const int grid = (BATCH * DHW) / 256;            // 16384
        icl_partial_kernel<<<grid, 256, 0, stream>>>(fwd, bwd, partial);
        icl_final_kernel<<<1, 256, 0, stream>>>(partial, grid, out);
    }
}